// Round 10
// baseline (11420.251 us; speedup 1.0000x reference)
//
#include <hip/hip_runtime.h>
#include <hip/hip_bf16.h>
#include <math.h>

#define IDIM 128
#define HDIM 512
#define SDIM 64
#define BATCH 128
#define MAXT 259
#define G4 2048
#define KTOT 704    // 128 (x) + 64 (rt) + 512 (h)
#define ROUT 194    // 64 + 128 + 2
#define AFRAG_U 73728   // 8 mt * 18 ks * 64 lanes * 8 e (uints, hi|lo packed) per buffer
#define NBLK 256

typedef __hip_bfloat16 bf16;
typedef __attribute__((ext_vector_type(8))) short short8;
typedef __attribute__((ext_vector_type(4))) float floatx4;

__device__ __forceinline__ float sigmoidf_(float v) { return 1.f / (1.f + expf(-v)); }
__device__ __forceinline__ float b2f(bf16 v) { return __bfloat162float(v); }
__device__ __forceinline__ float load_in(const void* p, size_t i, int isf32) {
    return isf32 ? ((const float*)p)[i] : b2f(((const bf16*)p)[i]);
}
__device__ __forceinline__ unsigned short f2bfbits(float v) {
    unsigned u = __builtin_bit_cast(unsigned, v);
    unsigned r = (u + 0x7FFFu + ((u >> 16) & 1u)) >> 16;
    return (unsigned short)r;
}
__device__ __forceinline__ float bfbits2f(unsigned short b) {
    return __builtin_bit_cast(float, (unsigned)b << 16);
}
__device__ __forceinline__ unsigned aload(const unsigned* p) {
    return __hip_atomic_load(p, __ATOMIC_RELAXED, __HIP_MEMORY_SCOPE_AGENT);
}
__device__ __forceinline__ unsigned long long aload64(const unsigned long long* p) {
    return __hip_atomic_load(p, __ATOMIC_RELAXED, __HIP_MEMORY_SCOPE_AGENT);
}
__device__ __forceinline__ void astore64(unsigned long long* p, unsigned long long v) {
    __hip_atomic_store(p, v, __ATOMIC_RELAXED, __HIP_MEMORY_SCOPE_AGENT);
}

// Fence-free grid barrier (R9-verified): relaxed-atomic flag array, per-wave
// vmcnt drain orders data stores before flag store. No __threadfence -> no L2
// writeback/invalidate. 256 blocks <= 256 CUs -> co-resident.
__device__ __forceinline__ void flag_barrier(unsigned* flags, unsigned epoch) {
    asm volatile("s_waitcnt vmcnt(0)" ::: "memory");
    __syncthreads();
    if (threadIdx.x == 0)
        __hip_atomic_store(&flags[blockIdx.x * 16], epoch,
                           __ATOMIC_RELAXED, __HIP_MEMORY_SCOPE_AGENT);
    while (aload(&flags[threadIdx.x * 16]) < epoch)
        __builtin_amdgcn_s_sleep(2);
    __atomic_signal_fence(__ATOMIC_SEQ_CST);
    __syncthreads();
}

// dtype detect (defensive): f32 data has random low halves -> bf16-exp >= 0x8F
__global__ void detect_kernel(const unsigned short* __restrict__ w, int* __restrict__ flag) {
    if (threadIdx.x == 0) {
        int isf32 = 0;
        for (int i = 0; i < 256; i++) {
            int e = (w[i] >> 7) & 0xFF;
            if (e >= 0x8F) isf32 = 1;
        }
        *flag = isf32;
    }
}

// Gate-interleaved combined weights in B-fragment layout (hi/lo bf16 split).
__global__ void prep_kernel(const void* __restrict__ Wih, const void* __restrict__ bih,
                            const void* __restrict__ Whh, const void* __restrict__ bhh,
                            unsigned short* __restrict__ WfH, unsigned short* __restrict__ WfL,
                            float* __restrict__ bc, const int* __restrict__ flag) {
    int isf32 = *flag;
    int jp = blockIdx.x;
    int u = jp >> 2, gate = jp & 3;
    int src = gate * HDIM + u;
    int jt = jp >> 4, jn = jp & 15;
    for (int k = threadIdx.x; k < KTOT; k += blockDim.x) {
        float v = (k < 192) ? load_in(Wih, (size_t)src * 192 + k, isf32)
                            : load_in(Whh, (size_t)src * HDIM + (k - 192), isf32);
        unsigned short hi = f2bfbits(v);
        unsigned short lo = f2bfbits(v - bfbits2f(hi));
        int ks = k >> 5, q = (k & 31) >> 3, e = k & 7;
        size_t d = (((size_t)jt * 22 + ks) * 64 + (q * 16 + jn)) * 8 + e;
        WfH[d] = hi;
        WfL[d] = lo;
    }
    if (threadIdx.x == 0)
        bc[jp] = load_in(bih, src, isf32) + load_in(bhh, src, isf32);
}

// Wr -> row-major bf16 hi/lo (208 rows, rows >=194 zero) + brf f32 (padded).
__global__ void wr_prep_kernel(const void* __restrict__ Wr, const void* __restrict__ br,
                               unsigned short* __restrict__ WrBh, unsigned short* __restrict__ WrBl,
                               float* __restrict__ brf, const int* __restrict__ flag) {
    int isf32 = *flag;
    int j = blockIdx.x;
    for (int k = threadIdx.x; k < HDIM; k += blockDim.x) {
        float v = (j < ROUT) ? load_in(Wr, (size_t)j * HDIM + k, isf32) : 0.f;
        unsigned short hi = f2bfbits(v);
        WrBh[(size_t)j * HDIM + k] = hi;
        WrBl[(size_t)j * HDIM + k] = f2bfbits(v - bfbits2f(hi));
    }
    if (threadIdx.x == 0) brf[j] = (j < ROUT) ? load_in(br, j, isf32) : 0.f;
}

// ---------------- persistent kernel, fence-free flag barrier ----------------
// 256 blocks x 256 threads. blk = ms*32+ns: gates tile rows 16ms..+15,
// j'-cols 64ns..+63 (wave wv owns n-tile ns*4+wv). Blocks 0..127 additionally
// run P2 for batch row blk. Cross-block traffic is ONLY the packed h/rt frag
// exchange (relaxed agent atomics, uint64): ~1.2 MB/step total.
__global__ __launch_bounds__(256) void persist_kernel(
        const void* __restrict__ x,
        const unsigned short* __restrict__ WfH, const unsigned short* __restrict__ WfL,
        const float* __restrict__ bc,
        const unsigned short* __restrict__ WrBh, const unsigned short* __restrict__ WrBl,
        const float* __restrict__ brf,
        unsigned* __restrict__ AfP,          // 2 x AFRAG_U uints (hi | lo<<16)
        unsigned short* __restrict__ Vg,     // [128][259][64] bf16, block-private
        void* __restrict__ dout, const int* __restrict__ flag,
        unsigned* __restrict__ flags) {
    __shared__ __align__(16) short Ahs[18 * 64 * 8];          // staged A hi (rt|h)
    __shared__ __align__(16) short Als[18 * 64 * 8];          // staged A lo
    __shared__ __align__(16) float scr[4][16][20];
    __shared__ __align__(16) float hl[16][17];
    __shared__ __align__(16) float hrow[HDIM];                // reconstructed h row (P2)
    __shared__ __align__(16) float outs[208];
    __shared__ __align__(16) float sL[324];
    __shared__ __align__(16) float aL[324];
    __shared__ __align__(16) float red[4][64];
    __shared__ __align__(16) float rts[64];
    __shared__ __align__(16) float brS[208];
    __shared__ __align__(16) float bcS[64];

    const int tid = threadIdx.x, lane = tid & 63, wv = tid >> 6;
    const int blk = blockIdx.x, ms = blk >> 5, ns = blk & 31;
    const int isf32 = *flag;

    for (int i = tid; i < 208; i += 256) brS[i] = brf[i];
    if (tid < 64) bcS[tid] = bc[ns * 64 + tid];
    for (int i = tid; i < 324; i += 256) { sL[i] = 0.f; aL[i] = 0.f; }
    float cc = 0.f;
    __syncthreads();

    const short8* WH = (const short8*)WfH;
    const short8* WL = (const short8*)WfL;
    const int nt = ns * 4 + wv;
    unsigned short* Vrow = Vg + (size_t)blk * MAXT * SDIM;    // blocks 0..127 only

    for (int t = 0; t < MAXT; t++) {
        const int cur = t & 1, nxt = cur ^ 1;
        const unsigned long long* AfPc64 =
            (const unsigned long long*)(AfP + (size_t)cur * AFRAG_U);
        unsigned long long* AfPn64 =
            (unsigned long long*)(AfP + (size_t)nxt * AFRAG_U);
        const int use_x = (t < 129);

        // ---- P0: stage A-frags (rt|h, 18 ks) packed->LDS via relaxed atomics ----
        for (int i = tid; i < 18 * 64; i += 256) {
            int ksi = i >> 6, l = i & 63;
            const unsigned long long* ap = AfPc64 + ((size_t)(ms * 18 + ksi) * 64 + l) * 4;
            short8 ah, al8;
            #pragma unroll
            for (int j = 0; j < 4; j++) {
                unsigned long long q = aload64(ap + j);
                unsigned u0 = (unsigned)q, u1 = (unsigned)(q >> 32);
                ah[2 * j]      = (short)(u0 & 0xffffu);
                al8[2 * j]     = (short)(u0 >> 16);
                ah[2 * j + 1]  = (short)(u1 & 0xffffu);
                al8[2 * j + 1] = (short)(u1 >> 16);
            }
            *(short8*)&Ahs[i * 8] = ah;
            *(short8*)&Als[i * 8] = al8;
        }
        __syncthreads();

        // ---- P1: gates MFMA (one 16x16 acc per wave) ----
        floatx4 acc = {0.f, 0.f, 0.f, 0.f};
        const short8* wb  = WH + (size_t)nt * 22 * 64;
        const short8* wbl = WL + (size_t)nt * 22 * 64;
        if (use_x) {
            int m = lane & 15, q = lane >> 4;
            size_t xrow = ((size_t)t * BATCH + ms * 16 + m) * IDIM + q * 8;
            #pragma unroll
            for (int ks = 0; ks < 4; ks++) {
                short8 a;
                if (isf32) {
                    const float* xf = (const float*)x + xrow + ks * 32;
                    #pragma unroll
                    for (int i = 0; i < 8; i++) a[i] = (short)f2bfbits(xf[i]);
                } else {
                    a = *(const short8*)((const unsigned short*)x + xrow + ks * 32);
                }
                acc = __builtin_amdgcn_mfma_f32_16x16x32_bf16(a, wb[ks * 64 + lane], acc, 0, 0, 0);
                if (isf32)
                    acc = __builtin_amdgcn_mfma_f32_16x16x32_bf16(a, wbl[ks * 64 + lane], acc, 0, 0, 0);
            }
        }
        #pragma unroll 6
        for (int ksi = 0; ksi < 18; ksi++) {
            int ks = 4 + ksi;
            short8 ah  = *(const short8*)&Ahs[(ksi * 64 + lane) * 8];
            short8 al8 = *(const short8*)&Als[(ksi * 64 + lane) * 8];
            short8 bh = wb[ks * 64 + lane];
            acc = __builtin_amdgcn_mfma_f32_16x16x32_bf16(ah, bh, acc, 0, 0, 0);
            acc = __builtin_amdgcn_mfma_f32_16x16x32_bf16(al8, bh, acc, 0, 0, 0);
            if (isf32)
                acc = __builtin_amdgcn_mfma_f32_16x16x32_bf16(ah, wbl[ks * 64 + lane], acc, 0, 0, 0);
        }
        {
            int n = lane & 15, m0 = (lane >> 4) * 4;
            #pragma unroll
            for (int r = 0; r < 4; r++) scr[wv][m0 + r][n] = acc[r];
        }
        __syncthreads();
        // cell epilogue: thread = (row r, local-u ul); c in one VGPR; h -> hl
        {
            int r = tid >> 4, ul = tid & 15;
            float4 g = *(const float4*)&scr[ul >> 2][r][(ul & 3) * 4];
            float4 bb = *(const float4*)&bcS[ul * 4];
            float c2 = sigmoidf_(g.y + bb.y) * cc + sigmoidf_(g.x + bb.x) * tanhf(g.z + bb.z);
            float h2 = sigmoidf_(g.w + bb.w) * tanhf(c2);
            cc = c2;
            hl[r][ul] = h2;
        }
        __syncthreads();
        // publish h tile as packed uint64 frag stores (128 threads, 2 vals each)
        if (tid < 128) {
            int r = tid >> 3, ulp = (tid & 7) * 2;
            float h0 = hl[r][ulp], h1 = hl[r][ulp + 1];
            unsigned short hb0 = f2bfbits(h0);
            unsigned short lb0 = f2bfbits(h0 - bfbits2f(hb0));
            unsigned short hb1 = f2bfbits(h1);
            unsigned short lb1 = f2bfbits(h1 - bfbits2f(hb1));
            unsigned u0 = (unsigned)hb0 | ((unsigned)lb0 << 16);
            unsigned u1 = (unsigned)hb1 | ((unsigned)lb1 << 16);
            int u_g = ns * 16 + ulp;
            int ksi2 = 2 + (u_g >> 5), q = (u_g & 31) >> 3, e = u_g & 7;
            size_t fi = (((size_t)ms * 18 + ksi2) * 64 + q * 16 + r) * 8 + e;
            astore64(AfPn64 + fi / 2, (unsigned long long)u0 | ((unsigned long long)u1 << 32));
        }
        flag_barrier(flags, 2 * t + 1);

        // ---- P2: row-blocks only ----
        if (blk < 128) {
            const int brow = blk;
            const int msb = brow >> 4, mloc = brow & 15;
            // stage h row: 256 uint64 atomic loads -> hrow f32
            {
                int ksi = 2 + (tid >> 4);
                int rem = tid & 15, q = rem >> 2, ep = (rem & 3) * 2;
                size_t fi = (((size_t)msb * 18 + ksi) * 64 + q * 16 + mloc) * 8 + ep;
                unsigned long long v = aload64(AfPn64 + fi / 2);
                unsigned u0 = (unsigned)v, u1 = (unsigned)(v >> 32);
                int k = (ksi - 2) * 32 + q * 8 + ep;
                hrow[k]     = bfbits2f((unsigned short)(u0 & 0xffffu))
                            + bfbits2f((unsigned short)(u0 >> 16));
                hrow[k + 1] = bfbits2f((unsigned short)(u1 & 0xffffu))
                            + bfbits2f((unsigned short)(u1 >> 16));
            }
            __syncthreads();
            // readout: wave-per-j dots vs cached Wr (read-only, L2-resident)
            {
                float hv[8];
                const float* hp = &hrow[lane * 8];
                #pragma unroll
                for (int i = 0; i < 8; i++) hv[i] = hp[i];
                for (int j = wv; j < 208; j += 4) {
                    short8 w8 = *(const short8*)(WrBh + (size_t)j * HDIM + lane * 8);
                    float p = 0.f;
                    #pragma unroll
                    for (int i = 0; i < 8; i++)
                        p += bfbits2f((unsigned short)w8[i]) * hv[i];
                    if (isf32) {
                        short8 wl8 = *(const short8*)(WrBl + (size_t)j * HDIM + lane * 8);
                        #pragma unroll
                        for (int i = 0; i < 8; i++)
                            p += bfbits2f((unsigned short)wl8[i]) * hv[i];
                    }
                    #pragma unroll
                    for (int off = 32; off; off >>= 1) p += __shfl_down(p, off, 64);
                    if (lane == 0) outs[j] = p + brS[j];
                }
            }
            __syncthreads();
            if (wv == 0) {
                float uval = sigmoidf_(outs[192]);
                float dval = sigmoidf_(outs[193]);
                Vrow[t * SDIM + lane] = f2bfbits(outs[lane]);
                int ebase = lane * 5;
                float sv[5], suf[5];
                #pragma unroll
                for (int j = 0; j < 5; j++) {
                    int e = ebase + j;
                    sv[j] = (e < MAXT) ? sL[e] : 0.f;
                }
                suf[4] = sv[4];
                #pragma unroll
                for (int j = 3; j >= 0; j--) suf[j] = sv[j] + suf[j + 1];
                float ltot = suf[0];
                float accs = ltot;
                #pragma unroll
                for (int off = 1; off < 64; off <<= 1) {
                    float y = __shfl_down(accs, off, 64);
                    if (lane + off < 64) accs += y;
                }
                float after_lane = accs - ltot;
                #pragma unroll
                for (int j = 0; j < 5; j++) {
                    int e = ebase + j;
                    if (e < MAXT) {
                        float prod = after_lane + (suf[j] - sv[j]);
                        float sp = (e == t) ? dval
                                            : fmaxf(0.f, sv[j] - fmaxf(0.f, uval - prod));
                        float inner = fmaxf(0.f, 1.f - prod - sp);
                        sL[e] = sp;
                        aL[e] = fminf(sp, inner);
                    }
                }
            }
            __syncthreads();
            {
                float racc = 0.f;
                for (int i2 = wv; i2 <= t; i2 += 4)
                    racc += aL[i2] * bfbits2f(Vrow[i2 * SDIM + lane]);
                red[wv][lane] = racc;
            }
            __syncthreads();
            if (wv == 0) {
                float rtv = red[0][lane] + red[1][lane] + red[2][lane] + red[3][lane];
                rts[lane] = rtv;
                // pack rt pairs -> uint64 frag stores (lanes 0..31)
                if (lane < 32) {
                    int d0 = lane * 2;
                    float r0 = rts[d0], r1 = rts[d0 + 1];
                    unsigned short hb0 = f2bfbits(r0);
                    unsigned short lb0 = f2bfbits(r0 - bfbits2f(hb0));
                    unsigned short hb1 = f2bfbits(r1);
                    unsigned short lb1 = f2bfbits(r1 - bfbits2f(hb1));
                    unsigned u0 = (unsigned)hb0 | ((unsigned)lb0 << 16);
                    unsigned u1 = (unsigned)hb1 | ((unsigned)lb1 << 16);
                    int ksi = d0 >> 5, q = (d0 & 31) >> 3, e = d0 & 7;
                    size_t fi = (((size_t)msb * 18 + ksi) * 64 + q * 16 + mloc) * 8 + e;
                    astore64(AfPn64 + fi / 2,
                             (unsigned long long)u0 | ((unsigned long long)u1 << 32));
                }
            } else if (wv == 1 && t >= 129) {
                float a = outs[64 + lane];
                float bvv = outs[128 + lane];
                float m = fmaxf(a, bvv);
                #pragma unroll
                for (int off = 32; off; off >>= 1) m = fmaxf(m, __shfl_xor(m, off, 64));
                float e = expf(a - m) + expf(bvv - m);
                #pragma unroll
                for (int off = 32; off; off >>= 1) e += __shfl_xor(e, off, 64);
                float ls = logf(e) + m;
                size_t base = ((size_t)(t - 129) * BATCH + brow) * IDIM;
                if (isf32) {
                    ((float*)dout)[base + lane] = a - ls;
                    ((float*)dout)[base + lane + 64] = bvv - ls;
                } else {
                    ((bf16*)dout)[base + lane] = __float2bfloat16(a - ls);
                    ((bf16*)dout)[base + lane + 64] = __float2bfloat16(bvv - ls);
                }
            }
        }
        flag_barrier(flags, 2 * t + 2);
    }
}

extern "C" void kernel_launch(void* const* d_in, const int* in_sizes, int n_in,
                              void* d_out, int out_size, void* d_ws, size_t ws_size,
                              hipStream_t stream) {
    const void* x   = d_in[0];
    const void* Wih = d_in[1];
    const void* bih = d_in[2];
    const void* Whh = d_in[3];
    const void* bhh = d_in[4];
    const void* Wr  = d_in[5];
    const void* br  = d_in[6];

    char* base = (char*)d_ws;
    size_t off = 0;
    int* flag = (int*)base;                                   off += 64;
    unsigned* flags = (unsigned*)(base + off);                off += 256 * 64 + 64;
    unsigned short* WfH  = (unsigned short*)(base + off);     off += (size_t)G4 * KTOT * 2;
    unsigned short* WfL  = (unsigned short*)(base + off);     off += (size_t)G4 * KTOT * 2;
    unsigned short* WrBh = (unsigned short*)(base + off);     off += (size_t)208 * HDIM * 2;
    unsigned short* WrBl = (unsigned short*)(base + off);     off += (size_t)208 * HDIM * 2;
    float* bc   = (float*)(base + off);                       off += G4 * 4;
    float* brf  = (float*)(base + off);                       off += 1024;
    unsigned* AfP = (unsigned*)(base + off);                  size_t af_off = off;
                                                              off += (size_t)2 * AFRAG_U * 4;
    unsigned short* Vg = (unsigned short*)(base + off);       off += (size_t)BATCH * MAXT * SDIM * 2;
    // total ~11 MB

    hipMemsetAsync(base + 64, 0, 256 * 64 + 64, stream);               // barrier flags
    hipMemsetAsync(base + af_off, 0, (size_t)2 * AFRAG_U * 4, stream); // A-frag buffers

    detect_kernel<<<1, 64, 0, stream>>>((const unsigned short*)Wih, flag);
    prep_kernel<<<G4, 256, 0, stream>>>(Wih, bih, Whh, bhh, WfH, WfL, bc, flag);
    wr_prep_kernel<<<208, 256, 0, stream>>>(Wr, br, WrBh, WrBl, brf, flag);

    persist_kernel<<<NBLK, 256, 0, stream>>>(x, WfH, WfL, bc, WrBh, WrBl, brf,
                                             AfP, Vg, d_out, flag, flags);

    (void)in_sizes; (void)n_in; (void)out_size; (void)ws_size;
}

// Round 11
// 5646.715 us; speedup vs baseline: 2.0225x; 2.0225x over previous
//
#include <hip/hip_runtime.h>
#include <hip/hip_bf16.h>
#include <math.h>

#define IDIM 128
#define HDIM 512
#define SDIM 64
#define BATCH 128
#define MAXT 259
#define G4 2048
#define KTOT 704    // 128 (x) + 64 (rt) + 512 (h)
#define ROUT 194    // 64 + 128 + 2
#define AFRAG_U 73728   // 8 mt * 18 ks * 64 lanes * 8 e (uints, hi|lo packed) per buffer
#define NBLK 256
#define PJ 224      // padded j-dim of part (16 thread-groups x 14 j, 8B-aligned pairs)

typedef __hip_bfloat16 bf16;
typedef __attribute__((ext_vector_type(8))) short short8;
typedef __attribute__((ext_vector_type(4))) float floatx4;

__device__ __forceinline__ float sigmoidf_(float v) { return 1.f / (1.f + expf(-v)); }
__device__ __forceinline__ float b2f(bf16 v) { return __bfloat162float(v); }
__device__ __forceinline__ float load_in(const void* p, size_t i, int isf32) {
    return isf32 ? ((const float*)p)[i] : b2f(((const bf16*)p)[i]);
}
__device__ __forceinline__ unsigned short f2bfbits(float v) {
    unsigned u = __builtin_bit_cast(unsigned, v);
    unsigned r = (u + 0x7FFFu + ((u >> 16) & 1u)) >> 16;
    return (unsigned short)r;
}
__device__ __forceinline__ float bfbits2f(unsigned short b) {
    return __builtin_bit_cast(float, (unsigned)b << 16);
}
__device__ __forceinline__ unsigned aload(const unsigned* p) {
    return __hip_atomic_load(p, __ATOMIC_RELAXED, __HIP_MEMORY_SCOPE_AGENT);
}
__device__ __forceinline__ unsigned long long aload64(const unsigned long long* p) {
    return __hip_atomic_load(p, __ATOMIC_RELAXED, __HIP_MEMORY_SCOPE_AGENT);
}
__device__ __forceinline__ void astore64(unsigned long long* p, unsigned long long v) {
    __hip_atomic_store(p, v, __ATOMIC_RELAXED, __HIP_MEMORY_SCOPE_AGENT);
}
__device__ __forceinline__ unsigned long long packf2(float a, float b) {
    return (unsigned long long)__builtin_bit_cast(unsigned, a)
         | ((unsigned long long)__builtin_bit_cast(unsigned, b) << 32);
}

// Fence-free grid barrier (R9-verified): relaxed-atomic flag array, per-wave
// vmcnt drain orders data stores before flag store. No __threadfence -> no L2
// writeback/invalidate. 256 blocks <= 256 CUs -> co-resident.
__device__ __forceinline__ void flag_barrier(unsigned* flags, unsigned epoch) {
    asm volatile("s_waitcnt vmcnt(0)" ::: "memory");
    __syncthreads();
    if (threadIdx.x == 0)
        __hip_atomic_store(&flags[blockIdx.x * 16], epoch,
                           __ATOMIC_RELAXED, __HIP_MEMORY_SCOPE_AGENT);
    while (aload(&flags[threadIdx.x * 16]) < epoch)
        __builtin_amdgcn_s_sleep(2);
    __atomic_signal_fence(__ATOMIC_SEQ_CST);
    __syncthreads();
}

// dtype detect (defensive): f32 data has random low halves -> bf16-exp >= 0x8F
__global__ void detect_kernel(const unsigned short* __restrict__ w, int* __restrict__ flag) {
    if (threadIdx.x == 0) {
        int isf32 = 0;
        for (int i = 0; i < 256; i++) {
            int e = (w[i] >> 7) & 0xFF;
            if (e >= 0x8F) isf32 = 1;
        }
        *flag = isf32;
    }
}

// Gate-interleaved combined weights in B-fragment layout (hi/lo bf16 split).
__global__ void prep_kernel(const void* __restrict__ Wih, const void* __restrict__ bih,
                            const void* __restrict__ Whh, const void* __restrict__ bhh,
                            unsigned short* __restrict__ WfH, unsigned short* __restrict__ WfL,
                            float* __restrict__ bc, const int* __restrict__ flag) {
    int isf32 = *flag;
    int jp = blockIdx.x;
    int u = jp >> 2, gate = jp & 3;
    int src = gate * HDIM + u;
    int jt = jp >> 4, jn = jp & 15;
    for (int k = threadIdx.x; k < KTOT; k += blockDim.x) {
        float v = (k < 192) ? load_in(Wih, (size_t)src * 192 + k, isf32)
                            : load_in(Whh, (size_t)src * HDIM + (k - 192), isf32);
        unsigned short hi = f2bfbits(v);
        unsigned short lo = f2bfbits(v - bfbits2f(hi));
        int ks = k >> 5, q = (k & 31) >> 3, e = k & 7;
        size_t d = (((size_t)jt * 22 + ks) * 64 + (q * 16 + jn)) * 8 + e;
        WfH[d] = hi;
        WfL[d] = lo;
    }
    if (threadIdx.x == 0)
        bc[jp] = load_in(bih, src, isf32) + load_in(bhh, src, isf32);
}

// Wr -> row-major bf16 hi/lo (208 rows, rows >=194 zero) + brf f32 (padded).
__global__ void wr_prep_kernel(const void* __restrict__ Wr, const void* __restrict__ br,
                               unsigned short* __restrict__ WrBh, unsigned short* __restrict__ WrBl,
                               float* __restrict__ brf, const int* __restrict__ flag) {
    int isf32 = *flag;
    int j = blockIdx.x;
    for (int k = threadIdx.x; k < HDIM; k += blockDim.x) {
        float v = (j < ROUT) ? load_in(Wr, (size_t)j * HDIM + k, isf32) : 0.f;
        unsigned short hi = f2bfbits(v);
        WrBh[(size_t)j * HDIM + k] = hi;
        WrBl[(size_t)j * HDIM + k] = f2bfbits(v - bfbits2f(hi));
    }
    if (threadIdx.x == 0) brf[j] = (j < ROUT) ? load_in(br, j, isf32) : 0.f;
}

// ---------------- persistent kernel (R9 structure, packed exchanges) ----------------
// 256 blocks x 256 threads. blk = ms*32+ns: gates tile rows 16ms..+15,
// j'-cols 64ns..+63 (wave wv owns n-tile ns*4+wv). Blocks 0..127 additionally
// run P2 for batch row blk. Cross-block data via relaxed agent atomics only.
__global__ __launch_bounds__(256) void persist_kernel(
        const void* __restrict__ x,
        const unsigned short* __restrict__ WfH, const unsigned short* __restrict__ WfL,
        const float* __restrict__ bc,
        const unsigned short* __restrict__ WrBh, const unsigned short* __restrict__ WrBl,
        const float* __restrict__ brf,
        unsigned* __restrict__ AfP,          // 2 x AFRAG_U uints (hi | lo<<16)
        float* __restrict__ part,            // [128 rows][32 ns][PJ j] f32
        unsigned short* __restrict__ Vg,     // [128][259][64] bf16, block-private
        void* __restrict__ dout, const int* __restrict__ flag,
        unsigned* __restrict__ flags) {
    __shared__ __align__(16) short Ahs[18 * 64 * 8];          // staged A hi (rt|h)
    __shared__ __align__(16) short Als[18 * 64 * 8];          // staged A lo
    __shared__ __align__(16) unsigned short wrsl[208 * 16];   // Wr hi slice (16 cols of ns)
    __shared__ __align__(16) unsigned short wrslL[208 * 16];  // Wr lo slice
    __shared__ __align__(16) float scr[4][16][20];
    __shared__ __align__(16) float hl[16][17];
    __shared__ __align__(16) float outs[208];
    __shared__ __align__(16) float sL[324];
    __shared__ __align__(16) float aL[324];
    __shared__ __align__(16) float red[4][64];
    __shared__ __align__(16) float brS[208];
    __shared__ __align__(16) float bcS[64];

    const int tid = threadIdx.x, lane = tid & 63, wv = tid >> 6;
    const int blk = blockIdx.x, ms = blk >> 5, ns = blk & 31;
    const int isf32 = *flag;

    for (int i = tid; i < 208 * 16; i += 256) {
        int j = i >> 4, ui = i & 15;
        wrsl[i]  = WrBh[(size_t)j * HDIM + ns * 16 + ui];
        wrslL[i] = WrBl[(size_t)j * HDIM + ns * 16 + ui];
    }
    for (int i = tid; i < 208; i += 256) brS[i] = brf[i];
    if (tid < 64) bcS[tid] = bc[ns * 64 + tid];
    for (int i = tid; i < 324; i += 256) { sL[i] = 0.f; aL[i] = 0.f; }
    float cc = 0.f;
    __syncthreads();

    const short8* WH = (const short8*)WfH;
    const short8* WL = (const short8*)WfL;
    const int nt = ns * 4 + wv;
    unsigned short* Vrow = Vg + (size_t)blk * MAXT * SDIM;    // blocks 0..127 only

    for (int t = 0; t < MAXT; t++) {
        const int cur = t & 1, nxt = cur ^ 1;
        const unsigned long long* AfPc64 =
            (const unsigned long long*)(AfP + (size_t)cur * AFRAG_U);
        unsigned long long* AfPn64 =
            (unsigned long long*)(AfP + (size_t)nxt * AFRAG_U);
        const int use_x = (t < 129);

        // ---- P0: stage A-frags (rt|h, 18 ks) packed->LDS via relaxed atomics ----
        for (int i = tid; i < 18 * 64; i += 256) {
            int ksi = i >> 6, l = i & 63;
            const unsigned long long* ap = AfPc64 + ((size_t)(ms * 18 + ksi) * 64 + l) * 4;
            short8 ah, al8;
            #pragma unroll
            for (int j = 0; j < 4; j++) {
                unsigned long long q = aload64(ap + j);
                unsigned u0 = (unsigned)q, u1 = (unsigned)(q >> 32);
                ah[2 * j]      = (short)(u0 & 0xffffu);
                al8[2 * j]     = (short)(u0 >> 16);
                ah[2 * j + 1]  = (short)(u1 & 0xffffu);
                al8[2 * j + 1] = (short)(u1 >> 16);
            }
            *(short8*)&Ahs[i * 8] = ah;
            *(short8*)&Als[i * 8] = al8;
        }
        __syncthreads();

        // ---- P1: gates MFMA (one 16x16 acc per wave) ----
        floatx4 acc = {0.f, 0.f, 0.f, 0.f};
        const short8* wb  = WH + (size_t)nt * 22 * 64;
        const short8* wbl = WL + (size_t)nt * 22 * 64;
        if (use_x) {
            int m = lane & 15, q = lane >> 4;
            size_t xrow = ((size_t)t * BATCH + ms * 16 + m) * IDIM + q * 8;
            #pragma unroll
            for (int ks = 0; ks < 4; ks++) {
                short8 a;
                if (isf32) {
                    const float* xf = (const float*)x + xrow + ks * 32;
                    #pragma unroll
                    for (int i = 0; i < 8; i++) a[i] = (short)f2bfbits(xf[i]);
                } else {
                    a = *(const short8*)((const unsigned short*)x + xrow + ks * 32);
                }
                acc = __builtin_amdgcn_mfma_f32_16x16x32_bf16(a, wb[ks * 64 + lane], acc, 0, 0, 0);
                if (isf32)
                    acc = __builtin_amdgcn_mfma_f32_16x16x32_bf16(a, wbl[ks * 64 + lane], acc, 0, 0, 0);
            }
        }
        #pragma unroll 6
        for (int ksi = 0; ksi < 18; ksi++) {
            int ks = 4 + ksi;
            short8 ah  = *(const short8*)&Ahs[(ksi * 64 + lane) * 8];
            short8 al8 = *(const short8*)&Als[(ksi * 64 + lane) * 8];
            short8 bh = wb[ks * 64 + lane];
            acc = __builtin_amdgcn_mfma_f32_16x16x32_bf16(ah, bh, acc, 0, 0, 0);
            acc = __builtin_amdgcn_mfma_f32_16x16x32_bf16(al8, bh, acc, 0, 0, 0);
            if (isf32)
                acc = __builtin_amdgcn_mfma_f32_16x16x32_bf16(ah, wbl[ks * 64 + lane], acc, 0, 0, 0);
        }
        {
            int n = lane & 15, m0 = (lane >> 4) * 4;
            #pragma unroll
            for (int r = 0; r < 4; r++) scr[wv][m0 + r][n] = acc[r];
        }
        __syncthreads();
        // cell epilogue: thread = (row r, local-u ul); c in one VGPR; h -> hl
        {
            int r = tid >> 4, ul = tid & 15;
            float4 g = *(const float4*)&scr[ul >> 2][r][(ul & 3) * 4];
            float4 bb = *(const float4*)&bcS[ul * 4];
            float c2 = sigmoidf_(g.y + bb.y) * cc + sigmoidf_(g.x + bb.x) * tanhf(g.z + bb.z);
            float h2 = sigmoidf_(g.w + bb.w) * tanhf(c2);
            cc = c2;
            hl[r][ul] = h2;
        }
        __syncthreads();
        // publish h tile as packed uint64 frag stores (128 threads; R10-verified)
        if (tid < 128) {
            int r = tid >> 3, ulp = (tid & 7) * 2;
            float h0 = hl[r][ulp], h1 = hl[r][ulp + 1];
            unsigned short hb0 = f2bfbits(h0);
            unsigned short lb0 = f2bfbits(h0 - bfbits2f(hb0));
            unsigned short hb1 = f2bfbits(h1);
            unsigned short lb1 = f2bfbits(h1 - bfbits2f(hb1));
            unsigned u0 = (unsigned)hb0 | ((unsigned)lb0 << 16);
            unsigned u1 = (unsigned)hb1 | ((unsigned)lb1 << 16);
            int u_g = ns * 16 + ulp;
            int ksi2 = 2 + (u_g >> 5), q = (u_g & 31) >> 3, e = u_g & 7;
            size_t fi = (((size_t)ms * 18 + ksi2) * 64 + q * 16 + r) * 8 + e;
            astore64(AfPn64 + fi / 2, (unsigned long long)u0 | ((unsigned long long)u1 << 32));
        }
        // readout partials: 16 rows x 14 j per thread (j = jset*14 + i), stored
        // as 7 uint64 f32-pairs -> ~halves atomic transactions vs R9.
        {
            int jset = tid >> 4, r2 = tid & 15;
            int row = ms * 16 + r2;
            unsigned long long* pb64 = (unsigned long long*)
                (part + (((size_t)row * 32) + ns) * PJ + jset * 14);
            #pragma unroll
            for (int i = 0; i < 7; i++) {
                int j0 = jset * 14 + 2 * i;
                if (j0 >= 208) break;
                float p0 = 0.f, p1 = 0.f;
                #pragma unroll
                for (int k = 0; k < 16; k++) {
                    float hv = hl[r2][k];
                    p0 += bfbits2f(wrsl[j0 * 16 + k]) * hv;
                    p1 += bfbits2f(wrsl[(j0 + 1) * 16 + k]) * hv;
                }
                if (isf32) {
                    #pragma unroll
                    for (int k = 0; k < 16; k++) {
                        float hv = hl[r2][k];
                        p0 += bfbits2f(wrslL[j0 * 16 + k]) * hv;
                        p1 += bfbits2f(wrslL[(j0 + 1) * 16 + k]) * hv;
                    }
                }
                astore64(pb64 + i, packf2(p0, p1));
            }
        }
        flag_barrier(flags, 2 * t + 1);

        // ---- P2: row-blocks only ----
        if (blk < 128) {
            const int brow = blk;
            const int msb = brow >> 4, mloc = brow & 15;
            if (tid < 208) {
                float s4 = brS[tid];
                const unsigned* pb = (const unsigned*)part + ((size_t)brow * 32) * PJ + tid;
                #pragma unroll 8
                for (int nsI = 0; nsI < 32; nsI++)
                    s4 += __builtin_bit_cast(float, aload(pb + (size_t)nsI * PJ));
                outs[tid] = s4;
            }
            __syncthreads();
            if (wv == 0) {
                float uval = sigmoidf_(outs[192]);
                float dval = sigmoidf_(outs[193]);
                Vrow[t * SDIM + lane] = f2bfbits(outs[lane]);
                int ebase = lane * 5;
                float sv[5], suf[5];
                #pragma unroll
                for (int j = 0; j < 5; j++) {
                    int e = ebase + j;
                    sv[j] = (e < MAXT) ? sL[e] : 0.f;
                }
                suf[4] = sv[4];
                #pragma unroll
                for (int j = 3; j >= 0; j--) suf[j] = sv[j] + suf[j + 1];
                float ltot = suf[0];
                float accs = ltot;
                #pragma unroll
                for (int off = 1; off < 64; off <<= 1) {
                    float y = __shfl_down(accs, off, 64);
                    if (lane + off < 64) accs += y;
                }
                float after_lane = accs - ltot;
                #pragma unroll
                for (int j = 0; j < 5; j++) {
                    int e = ebase + j;
                    if (e < MAXT) {
                        float prod = after_lane + (suf[j] - sv[j]);
                        float sp = (e == t) ? dval
                                            : fmaxf(0.f, sv[j] - fmaxf(0.f, uval - prod));
                        float inner = fmaxf(0.f, 1.f - prod - sp);
                        sL[e] = sp;
                        aL[e] = fminf(sp, inner);
                    }
                }
            }
            __syncthreads();
            {
                float racc = 0.f;
                for (int i2 = wv; i2 <= t; i2 += 4)
                    racc += aL[i2] * bfbits2f(Vrow[i2 * SDIM + lane]);
                red[wv][lane] = racc;
            }
            __syncthreads();
            if (wv == 0) {
                float rtv = red[0][lane] + red[1][lane] + red[2][lane] + red[3][lane];
                // pair rt via intra-wave shuffle -> 32 uint64 frag stores
                float rtn = __shfl_down(rtv, 1, 64);
                if ((lane & 1) == 0) {
                    unsigned short hb0 = f2bfbits(rtv);
                    unsigned short lb0 = f2bfbits(rtv - bfbits2f(hb0));
                    unsigned short hb1 = f2bfbits(rtn);
                    unsigned short lb1 = f2bfbits(rtn - bfbits2f(hb1));
                    unsigned u0 = (unsigned)hb0 | ((unsigned)lb0 << 16);
                    unsigned u1 = (unsigned)hb1 | ((unsigned)lb1 << 16);
                    int d0 = lane;
                    int ksi = d0 >> 5, q = (d0 & 31) >> 3, e = d0 & 7;
                    size_t fi = (((size_t)msb * 18 + ksi) * 64 + q * 16 + mloc) * 8 + e;
                    astore64(AfPn64 + fi / 2,
                             (unsigned long long)u0 | ((unsigned long long)u1 << 32));
                }
            } else if (wv == 1 && t >= 129) {
                float a = outs[64 + lane];
                float bvv = outs[128 + lane];
                float m = fmaxf(a, bvv);
                #pragma unroll
                for (int off = 32; off; off >>= 1) m = fmaxf(m, __shfl_xor(m, off, 64));
                float e = expf(a - m) + expf(bvv - m);
                #pragma unroll
                for (int off = 32; off; off >>= 1) e += __shfl_xor(e, off, 64);
                float ls = logf(e) + m;
                size_t base = ((size_t)(t - 129) * BATCH + brow) * IDIM;
                if (isf32) {
                    ((float*)dout)[base + lane] = a - ls;
                    ((float*)dout)[base + lane + 64] = bvv - ls;
                } else {
                    ((bf16*)dout)[base + lane] = __float2bfloat16(a - ls);
                    ((bf16*)dout)[base + lane + 64] = __float2bfloat16(bvv - ls);
                }
            }
        }
        flag_barrier(flags, 2 * t + 2);
    }
}

extern "C" void kernel_launch(void* const* d_in, const int* in_sizes, int n_in,
                              void* d_out, int out_size, void* d_ws, size_t ws_size,
                              hipStream_t stream) {
    const void* x   = d_in[0];
    const void* Wih = d_in[1];
    const void* bih = d_in[2];
    const void* Whh = d_in[3];
    const void* bhh = d_in[4];
    const void* Wr  = d_in[5];
    const void* br  = d_in[6];

    char* base = (char*)d_ws;
    size_t off = 0;
    int* flag = (int*)base;                                   off += 64;
    unsigned* flags = (unsigned*)(base + off);                off += 256 * 64 + 64;
    unsigned short* WfH  = (unsigned short*)(base + off);     off += (size_t)G4 * KTOT * 2;
    unsigned short* WfL  = (unsigned short*)(base + off);     off += (size_t)G4 * KTOT * 2;
    unsigned short* WrBh = (unsigned short*)(base + off);     off += (size_t)208 * HDIM * 2;
    unsigned short* WrBl = (unsigned short*)(base + off);     off += (size_t)208 * HDIM * 2;
    float* bc   = (float*)(base + off);                       off += G4 * 4;
    float* brf  = (float*)(base + off);                       off += 1024;
    unsigned* AfP = (unsigned*)(base + off);                  size_t af_off = off;
                                                              off += (size_t)2 * AFRAG_U * 4;
    float* part = (float*)(base + off);                       off += (size_t)BATCH * 32 * PJ * 4;
    unsigned short* Vg = (unsigned short*)(base + off);       off += (size_t)BATCH * MAXT * SDIM * 2;
    // total ~15 MB

    hipMemsetAsync(base + 64, 0, 256 * 64 + 64, stream);               // barrier flags
    hipMemsetAsync(base + af_off, 0, (size_t)2 * AFRAG_U * 4, stream); // A-frag buffers

    detect_kernel<<<1, 64, 0, stream>>>((const unsigned short*)Wih, flag);
    prep_kernel<<<G4, 256, 0, stream>>>(Wih, bih, Whh, bhh, WfH, WfL, bc, flag);
    wr_prep_kernel<<<208, 256, 0, stream>>>(Wr, br, WrBh, WrBl, brf, flag);

    persist_kernel<<<NBLK, 256, 0, stream>>>(x, WfH, WfL, bc, WrBh, WrBl, brf,
                                             AfP, part, Vg, d_out, flag, flags);

    (void)in_sizes; (void)n_in; (void)out_size; (void)ws_size;
}

// Round 12
// 5569.648 us; speedup vs baseline: 2.0504x; 1.0138x over previous
//
#include <hip/hip_runtime.h>
#include <hip/hip_bf16.h>
#include <math.h>

#define IDIM 128
#define HDIM 512
#define SDIM 64
#define BATCH 128
#define MAXT 259
#define G4 2048
#define KTOT 704    // 128 (x) + 64 (rt) + 512 (h)
#define ROUT 194    // 64 + 128 + 2
#define AFRAG_U 73728   // 8 mt * 18 ks * 64 lanes * 8 e (uints, hi|lo packed) per buffer
#define NBLK 256
#define PJ 224      // padded j-dim of part (112 uint64 slots per (row,ns))

typedef __hip_bfloat16 bf16;
typedef __attribute__((ext_vector_type(8))) short short8;
typedef __attribute__((ext_vector_type(4))) float floatx4;

__device__ __forceinline__ float sigmoidf_(float v) { return 1.f / (1.f + expf(-v)); }
__device__ __forceinline__ float b2f(bf16 v) { return __bfloat162float(v); }
__device__ __forceinline__ float load_in(const void* p, size_t i, int isf32) {
    return isf32 ? ((const float*)p)[i] : b2f(((const bf16*)p)[i]);
}
__device__ __forceinline__ unsigned short f2bfbits(float v) {
    unsigned u = __builtin_bit_cast(unsigned, v);
    unsigned r = (u + 0x7FFFu + ((u >> 16) & 1u)) >> 16;
    return (unsigned short)r;
}
__device__ __forceinline__ float bfbits2f(unsigned short b) {
    return __builtin_bit_cast(float, (unsigned)b << 16);
}
__device__ __forceinline__ unsigned aload(const unsigned* p) {
    return __hip_atomic_load(p, __ATOMIC_RELAXED, __HIP_MEMORY_SCOPE_AGENT);
}
__device__ __forceinline__ unsigned long long aload64(const unsigned long long* p) {
    return __hip_atomic_load(p, __ATOMIC_RELAXED, __HIP_MEMORY_SCOPE_AGENT);
}
__device__ __forceinline__ void astore64(unsigned long long* p, unsigned long long v) {
    __hip_atomic_store(p, v, __ATOMIC_RELAXED, __HIP_MEMORY_SCOPE_AGENT);
}
__device__ __forceinline__ unsigned long long packf2(float a, float b) {
    return (unsigned long long)__builtin_bit_cast(unsigned, a)
         | ((unsigned long long)__builtin_bit_cast(unsigned, b) << 32);
}

// Fence-free grid barrier (R9-verified): relaxed-atomic flag array, per-wave
// vmcnt drain orders data stores before flag store. No __threadfence -> no L2
// writeback/invalidate. 256 blocks <= 256 CUs -> co-resident.
__device__ __forceinline__ void flag_barrier(unsigned* flags, unsigned epoch) {
    asm volatile("s_waitcnt vmcnt(0)" ::: "memory");
    __syncthreads();
    if (threadIdx.x == 0)
        __hip_atomic_store(&flags[blockIdx.x * 16], epoch,
                           __ATOMIC_RELAXED, __HIP_MEMORY_SCOPE_AGENT);
    while (aload(&flags[threadIdx.x * 16]) < epoch)
        __builtin_amdgcn_s_sleep(2);
    __atomic_signal_fence(__ATOMIC_SEQ_CST);
    __syncthreads();
}

// dtype detect (defensive): f32 data has random low halves -> bf16-exp >= 0x8F
__global__ void detect_kernel(const unsigned short* __restrict__ w, int* __restrict__ flag) {
    if (threadIdx.x == 0) {
        int isf32 = 0;
        for (int i = 0; i < 256; i++) {
            int e = (w[i] >> 7) & 0xFF;
            if (e >= 0x8F) isf32 = 1;
        }
        *flag = isf32;
    }
}

// Gate-interleaved combined weights in B-fragment layout (hi/lo bf16 split).
__global__ void prep_kernel(const void* __restrict__ Wih, const void* __restrict__ bih,
                            const void* __restrict__ Whh, const void* __restrict__ bhh,
                            unsigned short* __restrict__ WfH, unsigned short* __restrict__ WfL,
                            float* __restrict__ bc, const int* __restrict__ flag) {
    int isf32 = *flag;
    int jp = blockIdx.x;
    int u = jp >> 2, gate = jp & 3;
    int src = gate * HDIM + u;
    int jt = jp >> 4, jn = jp & 15;
    for (int k = threadIdx.x; k < KTOT; k += blockDim.x) {
        float v = (k < 192) ? load_in(Wih, (size_t)src * 192 + k, isf32)
                            : load_in(Whh, (size_t)src * HDIM + (k - 192), isf32);
        unsigned short hi = f2bfbits(v);
        unsigned short lo = f2bfbits(v - bfbits2f(hi));
        int ks = k >> 5, q = (k & 31) >> 3, e = k & 7;
        size_t d = (((size_t)jt * 22 + ks) * 64 + (q * 16 + jn)) * 8 + e;
        WfH[d] = hi;
        WfL[d] = lo;
    }
    if (threadIdx.x == 0)
        bc[jp] = load_in(bih, src, isf32) + load_in(bhh, src, isf32);
}

// Wr -> row-major bf16 hi/lo (208 rows, rows >=194 zero) + brf f32 (padded).
__global__ void wr_prep_kernel(const void* __restrict__ Wr, const void* __restrict__ br,
                               unsigned short* __restrict__ WrBh, unsigned short* __restrict__ WrBl,
                               float* __restrict__ brf, const int* __restrict__ flag) {
    int isf32 = *flag;
    int j = blockIdx.x;
    for (int k = threadIdx.x; k < HDIM; k += blockDim.x) {
        float v = (j < ROUT) ? load_in(Wr, (size_t)j * HDIM + k, isf32) : 0.f;
        unsigned short hi = f2bfbits(v);
        WrBh[(size_t)j * HDIM + k] = hi;
        WrBl[(size_t)j * HDIM + k] = f2bfbits(v - bfbits2f(hi));
    }
    if (threadIdx.x == 0) brf[j] = (j < ROUT) ? load_in(br, j, isf32) : 0.f;
}

// ---------------- persistent kernel (R11 + coalesced partial publish) ----------------
// 256 blocks x 256 threads. blk = ms*32+ns: gates tile rows 16ms..+15,
// j'-cols 64ns..+63 (wave wv owns n-tile ns*4+wv). Blocks 0..127 additionally
// run P2 for batch row blk. Cross-block data via relaxed agent atomics only.
// Partials computed into LDS, then published with lane-contiguous wave-wide
// uint64 stores (full 64B sectors -> no write amplification).
__global__ __launch_bounds__(256) void persist_kernel(
        const void* __restrict__ x,
        const unsigned short* __restrict__ WfH, const unsigned short* __restrict__ WfL,
        const float* __restrict__ bc,
        const unsigned short* __restrict__ WrBh, const unsigned short* __restrict__ WrBl,
        const float* __restrict__ brf,
        unsigned* __restrict__ AfP,          // 2 x AFRAG_U uints (hi | lo<<16)
        float* __restrict__ part,            // [128 rows][32 ns][PJ j] f32
        unsigned short* __restrict__ Vg,     // [128][259][64] bf16, block-private
        void* __restrict__ dout, const int* __restrict__ flag,
        unsigned* __restrict__ flags) {
    __shared__ __align__(16) short Ahs[18 * 64 * 8];          // staged A hi; pt overlay later
    __shared__ __align__(16) short Als[18 * 64 * 8];          // staged A lo
    __shared__ __align__(16) unsigned short wrsl[208 * 16];   // Wr hi slice (16 cols of ns)
    __shared__ __align__(16) unsigned short wrslL[208 * 16];  // Wr lo slice
    __shared__ __align__(16) float scr[4][16][20];
    __shared__ __align__(16) float hl[16][17];
    __shared__ __align__(16) float outs[208];
    __shared__ __align__(16) float sL[324];
    __shared__ __align__(16) float aL[324];
    __shared__ __align__(16) float red[4][64];
    __shared__ __align__(16) float brS[208];
    __shared__ __align__(16) float bcS[64];

    const int tid = threadIdx.x, lane = tid & 63, wv = tid >> 6;
    const int blk = blockIdx.x, ms = blk >> 5, ns = blk & 31;
    const int isf32 = *flag;
    float* const pt = (float*)Ahs;       // 16 x 212 f32 overlay (13.6KB <= 18.4KB)

    for (int i = tid; i < 208 * 16; i += 256) {
        int j = i >> 4, ui = i & 15;
        wrsl[i]  = WrBh[(size_t)j * HDIM + ns * 16 + ui];
        wrslL[i] = WrBl[(size_t)j * HDIM + ns * 16 + ui];
    }
    for (int i = tid; i < 208; i += 256) brS[i] = brf[i];
    if (tid < 64) bcS[tid] = bc[ns * 64 + tid];
    for (int i = tid; i < 324; i += 256) { sL[i] = 0.f; aL[i] = 0.f; }
    float cc = 0.f;
    __syncthreads();

    const short8* WH = (const short8*)WfH;
    const short8* WL = (const short8*)WfL;
    const int nt = ns * 4 + wv;
    unsigned short* Vrow = Vg + (size_t)blk * MAXT * SDIM;    // blocks 0..127 only

    for (int t = 0; t < MAXT; t++) {
        const int cur = t & 1, nxt = cur ^ 1;
        const unsigned long long* AfPc64 =
            (const unsigned long long*)(AfP + (size_t)cur * AFRAG_U);
        unsigned long long* AfPn64 =
            (unsigned long long*)(AfP + (size_t)nxt * AFRAG_U);
        const int use_x = (t < 129);

        // ---- P0: stage A-frags (rt|h, 18 ks) packed->LDS via relaxed atomics ----
        for (int i = tid; i < 18 * 64; i += 256) {
            int ksi = i >> 6, l = i & 63;
            const unsigned long long* ap = AfPc64 + ((size_t)(ms * 18 + ksi) * 64 + l) * 4;
            short8 ah, al8;
            #pragma unroll
            for (int j = 0; j < 4; j++) {
                unsigned long long q = aload64(ap + j);
                unsigned u0 = (unsigned)q, u1 = (unsigned)(q >> 32);
                ah[2 * j]      = (short)(u0 & 0xffffu);
                al8[2 * j]     = (short)(u0 >> 16);
                ah[2 * j + 1]  = (short)(u1 & 0xffffu);
                al8[2 * j + 1] = (short)(u1 >> 16);
            }
            *(short8*)&Ahs[i * 8] = ah;
            *(short8*)&Als[i * 8] = al8;
        }
        __syncthreads();

        // ---- P1: gates MFMA (one 16x16 acc per wave) ----
        floatx4 acc = {0.f, 0.f, 0.f, 0.f};
        const short8* wb  = WH + (size_t)nt * 22 * 64;
        const short8* wbl = WL + (size_t)nt * 22 * 64;
        if (use_x) {
            int m = lane & 15, q = lane >> 4;
            size_t xrow = ((size_t)t * BATCH + ms * 16 + m) * IDIM + q * 8;
            #pragma unroll
            for (int ks = 0; ks < 4; ks++) {
                short8 a;
                if (isf32) {
                    const float* xf = (const float*)x + xrow + ks * 32;
                    #pragma unroll
                    for (int i = 0; i < 8; i++) a[i] = (short)f2bfbits(xf[i]);
                } else {
                    a = *(const short8*)((const unsigned short*)x + xrow + ks * 32);
                }
                acc = __builtin_amdgcn_mfma_f32_16x16x32_bf16(a, wb[ks * 64 + lane], acc, 0, 0, 0);
                if (isf32)
                    acc = __builtin_amdgcn_mfma_f32_16x16x32_bf16(a, wbl[ks * 64 + lane], acc, 0, 0, 0);
            }
        }
        #pragma unroll 6
        for (int ksi = 0; ksi < 18; ksi++) {
            int ks = 4 + ksi;
            short8 ah  = *(const short8*)&Ahs[(ksi * 64 + lane) * 8];
            short8 al8 = *(const short8*)&Als[(ksi * 64 + lane) * 8];
            short8 bh = wb[ks * 64 + lane];
            acc = __builtin_amdgcn_mfma_f32_16x16x32_bf16(ah, bh, acc, 0, 0, 0);
            acc = __builtin_amdgcn_mfma_f32_16x16x32_bf16(al8, bh, acc, 0, 0, 0);
            if (isf32)
                acc = __builtin_amdgcn_mfma_f32_16x16x32_bf16(ah, wbl[ks * 64 + lane], acc, 0, 0, 0);
        }
        {
            int n = lane & 15, m0 = (lane >> 4) * 4;
            #pragma unroll
            for (int r = 0; r < 4; r++) scr[wv][m0 + r][n] = acc[r];
        }
        __syncthreads();
        // cell epilogue: thread = (row r, local-u ul); c in one VGPR; h -> hl
        {
            int r = tid >> 4, ul = tid & 15;
            float4 g = *(const float4*)&scr[ul >> 2][r][(ul & 3) * 4];
            float4 bb = *(const float4*)&bcS[ul * 4];
            float c2 = sigmoidf_(g.y + bb.y) * cc + sigmoidf_(g.x + bb.x) * tanhf(g.z + bb.z);
            float h2 = sigmoidf_(g.w + bb.w) * tanhf(c2);
            cc = c2;
            hl[r][ul] = h2;
        }
        __syncthreads();   // hl ready; Ahs (MFMA staging) now dead -> pt overlay OK
        // publish h tile as packed uint64 frag stores (128 threads; R10-verified)
        if (tid < 128) {
            int r = tid >> 3, ulp = (tid & 7) * 2;
            float h0 = hl[r][ulp], h1 = hl[r][ulp + 1];
            unsigned short hb0 = f2bfbits(h0);
            unsigned short lb0 = f2bfbits(h0 - bfbits2f(hb0));
            unsigned short hb1 = f2bfbits(h1);
            unsigned short lb1 = f2bfbits(h1 - bfbits2f(hb1));
            unsigned u0 = (unsigned)hb0 | ((unsigned)lb0 << 16);
            unsigned u1 = (unsigned)hb1 | ((unsigned)lb1 << 16);
            int u_g = ns * 16 + ulp;
            int ksi2 = 2 + (u_g >> 5), q = (u_g & 31) >> 3, e = u_g & 7;
            size_t fi = (((size_t)ms * 18 + ksi2) * 64 + q * 16 + r) * 8 + e;
            astore64(AfPn64 + fi / 2, (unsigned long long)u0 | ((unsigned long long)u1 << 32));
        }
        // readout partials -> LDS tile pt[16][212] (full f32)
        {
            int jset = tid >> 4, r2 = tid & 15;
            float* prow = pt + r2 * 212;
            #pragma unroll
            for (int i = 0; i < 13; i++) {
                int j = jset * 13 + i;
                float p = 0.f;
                #pragma unroll
                for (int k = 0; k < 16; k++) p += bfbits2f(wrsl[j * 16 + k]) * hl[r2][k];
                if (isf32) {
                    #pragma unroll
                    for (int k = 0; k < 16; k++) p += bfbits2f(wrslL[j * 16 + k]) * hl[r2][k];
                }
                prow[j] = p;
            }
        }
        __syncthreads();
        // coalesced publish: wave wv owns rows 4wv..4wv+3; per row two wave-wide
        // lane-contiguous uint64 stores (512B + 320B) -> full 64B sectors.
        {
            #pragma unroll
            for (int it = 0; it < 4; it++) {
                int rloc = wv * 4 + it;
                int row = ms * 16 + rloc;
                const float* pr = pt + rloc * 212;
                unsigned long long* pb64 =
                    (unsigned long long*)(part + (((size_t)row * 32) + ns) * PJ);
                astore64(pb64 + lane, packf2(pr[2 * lane], pr[2 * lane + 1]));
                if (lane < 40)
                    astore64(pb64 + 64 + lane,
                             packf2(pr[128 + 2 * lane], pr[129 + 2 * lane]));
            }
        }
        flag_barrier(flags, 2 * t + 1);

        // ---- P2: row-blocks only ----
        if (blk < 128) {
            const int brow = blk;
            const int msb = brow >> 4, mloc = brow & 15;
            if (tid < 208) {
                float s4 = brS[tid];
                const unsigned* pb = (const unsigned*)part + ((size_t)brow * 32) * PJ + tid;
                #pragma unroll 8
                for (int nsI = 0; nsI < 32; nsI++)
                    s4 += __builtin_bit_cast(float, aload(pb + (size_t)nsI * PJ));
                outs[tid] = s4;
            }
            __syncthreads();
            if (wv == 0) {
                float uval = sigmoidf_(outs[192]);
                float dval = sigmoidf_(outs[193]);
                Vrow[t * SDIM + lane] = f2bfbits(outs[lane]);
                int ebase = lane * 5;
                float sv[5], suf[5];
                #pragma unroll
                for (int j = 0; j < 5; j++) {
                    int e = ebase + j;
                    sv[j] = (e < MAXT) ? sL[e] : 0.f;
                }
                suf[4] = sv[4];
                #pragma unroll
                for (int j = 3; j >= 0; j--) suf[j] = sv[j] + suf[j + 1];
                float ltot = suf[0];
                float accs = ltot;
                #pragma unroll
                for (int off = 1; off < 64; off <<= 1) {
                    float y = __shfl_down(accs, off, 64);
                    if (lane + off < 64) accs += y;
                }
                float after_lane = accs - ltot;
                #pragma unroll
                for (int j = 0; j < 5; j++) {
                    int e = ebase + j;
                    if (e < MAXT) {
                        float prod = after_lane + (suf[j] - sv[j]);
                        float sp = (e == t) ? dval
                                            : fmaxf(0.f, sv[j] - fmaxf(0.f, uval - prod));
                        float inner = fmaxf(0.f, 1.f - prod - sp);
                        sL[e] = sp;
                        aL[e] = fminf(sp, inner);
                    }
                }
            }
            __syncthreads();
            {
                float racc = 0.f;
                for (int i2 = wv; i2 <= t; i2 += 4)
                    racc += aL[i2] * bfbits2f(Vrow[i2 * SDIM + lane]);
                red[wv][lane] = racc;
            }
            __syncthreads();
            if (wv == 0) {
                float rtv = red[0][lane] + red[1][lane] + red[2][lane] + red[3][lane];
                // pair rt via intra-wave shuffle -> 32 uint64 frag stores
                float rtn = __shfl_down(rtv, 1, 64);
                if ((lane & 1) == 0) {
                    unsigned short hb0 = f2bfbits(rtv);
                    unsigned short lb0 = f2bfbits(rtv - bfbits2f(hb0));
                    unsigned short hb1 = f2bfbits(rtn);
                    unsigned short lb1 = f2bfbits(rtn - bfbits2f(hb1));
                    unsigned u0 = (unsigned)hb0 | ((unsigned)lb0 << 16);
                    unsigned u1 = (unsigned)hb1 | ((unsigned)lb1 << 16);
                    int d0 = lane;
                    int ksi = d0 >> 5, q = (d0 & 31) >> 3, e = d0 & 7;
                    size_t fi = (((size_t)msb * 18 + ksi) * 64 + q * 16 + mloc) * 8 + e;
                    astore64(AfPn64 + fi / 2,
                             (unsigned long long)u0 | ((unsigned long long)u1 << 32));
                }
            } else if (wv == 1 && t >= 129) {
                float a = outs[64 + lane];
                float bvv = outs[128 + lane];
                float m = fmaxf(a, bvv);
                #pragma unroll
                for (int off = 32; off; off >>= 1) m = fmaxf(m, __shfl_xor(m, off, 64));
                float e = expf(a - m) + expf(bvv - m);
                #pragma unroll
                for (int off = 32; off; off >>= 1) e += __shfl_xor(e, off, 64);
                float ls = logf(e) + m;
                size_t base = ((size_t)(t - 129) * BATCH + brow) * IDIM;
                if (isf32) {
                    ((float*)dout)[base + lane] = a - ls;
                    ((float*)dout)[base + lane + 64] = bvv - ls;
                } else {
                    ((bf16*)dout)[base + lane] = __float2bfloat16(a - ls);
                    ((bf16*)dout)[base + lane + 64] = __float2bfloat16(bvv - ls);
                }
            }
        }
        flag_barrier(flags, 2 * t + 2);
    }
}

extern "C" void kernel_launch(void* const* d_in, const int* in_sizes, int n_in,
                              void* d_out, int out_size, void* d_ws, size_t ws_size,
                              hipStream_t stream) {
    const void* x   = d_in[0];
    const void* Wih = d_in[1];
    const void* bih = d_in[2];
    const void* Whh = d_in[3];
    const void* bhh = d_in[4];
    const void* Wr  = d_in[5];
    const void* br  = d_in[6];

    char* base = (char*)d_ws;
    size_t off = 0;
    int* flag = (int*)base;                                   off += 64;
    unsigned* flags = (unsigned*)(base + off);                off += 256 * 64 + 64;
    unsigned short* WfH  = (unsigned short*)(base + off);     off += (size_t)G4 * KTOT * 2;
    unsigned short* WfL  = (unsigned short*)(base + off);     off += (size_t)G4 * KTOT * 2;
    unsigned short* WrBh = (unsigned short*)(base + off);     off += (size_t)208 * HDIM * 2;
    unsigned short* WrBl = (unsigned short*)(base + off);     off += (size_t)208 * HDIM * 2;
    float* bc   = (float*)(base + off);                       off += G4 * 4;
    float* brf  = (float*)(base + off);                       off += 1024;
    unsigned* AfP = (unsigned*)(base + off);                  size_t af_off = off;
                                                              off += (size_t)2 * AFRAG_U * 4;
    float* part = (float*)(base + off);                       off += (size_t)BATCH * 32 * PJ * 4;
    unsigned short* Vg = (unsigned short*)(base + off);       off += (size_t)BATCH * MAXT * SDIM * 2;
    // total ~15 MB

    hipMemsetAsync(base + 64, 0, 256 * 64 + 64, stream);               // barrier flags
    hipMemsetAsync(base + af_off, 0, (size_t)2 * AFRAG_U * 4, stream); // A-frag buffers

    detect_kernel<<<1, 64, 0, stream>>>((const unsigned short*)Wih, flag);
    prep_kernel<<<G4, 256, 0, stream>>>(Wih, bih, Whh, bhh, WfH, WfL, bc, flag);
    wr_prep_kernel<<<208, 256, 0, stream>>>(Wr, br, WrBh, WrBl, brf, flag);

    persist_kernel<<<NBLK, 256, 0, stream>>>(x, WfH, WfL, bc, WrBh, WrBl, brf,
                                             AfP, part, Vg, d_out, flag, flags);

    (void)in_sizes; (void)n_in; (void)out_size; (void)ws_size;
}